// Round 2
// 269.836 us; speedup vs baseline: 1.0117x; 1.0117x over previous
//
#include <hip/hip_runtime.h>
#include <cstdint>

// Problem constants (reference: B=8, S=2048, D=1024, vocab=50257, p=0.1)
constexpr uint32_t D = 1024;
constexpr uint32_t S = 2048;
constexpr uint32_t TOTAL = 8u * 2048u * 1024u;   // 2^24 elements

// Native clang vector type — required by __builtin_nontemporal_store
// (HIP's float4 is a struct and is rejected by the builtin).
typedef float vf4 __attribute__((ext_vector_type(4)));

// ---------------------------------------------------------------------------
// JAX threefry2x32, key = jax.random.key(42) -> (k1,k2) = (0, 42).
// Partitionable random_bits, bit_width=32 (verified round 3, absmax 0.5):
//   bits[i] = out0 ^ out1 of threefry2x32((0,42), (0, i))
// DO NOT TOUCH: bit-pinned against the harness reference.
// ---------------------------------------------------------------------------
__device__ __forceinline__ uint32_t rotl32(uint32_t x, int r) {
    return (x << r) | (x >> (32 - r));
}

__device__ __forceinline__ uint32_t threefry_bits_xor(uint32_t ctr) {
    const uint32_t ks0 = 0u;
    const uint32_t ks1 = 42u;
    const uint32_t ks2 = 0x1BD11BDAu ^ 42u;
    uint32_t x0 = ks0;          // counts_hi = 0, + ks0
    uint32_t x1 = ctr + ks1;    // counts_lo = i, + ks1
#define RND(r) x0 += x1; x1 = rotl32(x1, r); x1 ^= x0;
    RND(13) RND(15) RND(26) RND(6)
    x0 += ks1; x1 += ks2 + 1u;
    RND(17) RND(29) RND(16) RND(24)
    x0 += ks2; x1 += ks0 + 2u;
    RND(13) RND(15) RND(26) RND(6)
    x0 += ks0; x1 += ks1 + 3u;
    RND(17) RND(29) RND(16) RND(24)
    x0 += ks1; x1 += ks2 + 4u;
    RND(13) RND(15) RND(26) RND(6)
    x0 += ks2; x1 += ks0 + 5u;
#undef RND
    return x0 ^ x1;
}

// ---------------------------------------------------------------------------
// Dropout keep test, integer domain (bit-exact transform of the f32 compare):
//   u = bitcast((bits>>9)|0x3F800000) - 1.0f  ==  (bits>>9) * 2^-23  (exact)
//   0.9f == 7549747 * 2^-23  (0x3F666666)
//   u < 0.9f  <=>  (bits>>9) < 7549747  <=>  bits < 7549747*512 = 0xE6666600
// ---------------------------------------------------------------------------
constexpr uint32_t KEEP_THRESH = 0xE6666600u;
constexpr float    KEEP_SCALE  = 1.0f / 0.9f;

// One thread handles 4 consecutive flat elements (same b,s; d..d+3).
// One 256-thread block covers exactly one (b,s) row of 1024 elements, so the
// token id is block-uniform -> compiler emits s_load + SGPR-based emb address.
__global__ __launch_bounds__(256) void emb_pe_drop_kernel(
    const int* __restrict__ idx,     // [8, 2048] token ids (int32)
    const float* __restrict__ emb,   // [50257, 1024]
    float* __restrict__ out)         // [8, 2048, 1024]
{
    const uint32_t row = blockIdx.x;            // 0..16383 == b*2048 + s
    const uint32_t d   = threadIdx.x << 2;      // 0..1020
    const uint32_t n   = (row << 10) | d;       // flat output index

    // Block-uniform token fetch (scalar path).
    const int tok = idx[row];
    const vf4 e = *reinterpret_cast<const vf4*>(
        emb + (size_t)(uint32_t)tok * D + d);

    // pe[s, 2i]   = sin(s * 10000^(-2i/1024)),  pe[s, 2i+1] = cos(...)
    // angle in revolutions: rev = s * exp2(ii*cc + KK), KK = -log2(2*pi)
    const float cc = -0.02595256324130751f;     // -log2(10000)/512
    const float KK = -2.6514961294723187f;      // -log2(2*pi)
    const float R1 = 0.98217188f;               // 10000^(-1/512) = 2^cc
    const float ii = (float)(threadIdx.x << 1); // d >> 1
    float invr0 = __builtin_amdgcn_exp2f(fmaf(ii, cc, KK));
    float invr1 = invr0 * R1;                   // saves one quarter-rate exp2
    const float pos = (float)(row & (S - 1u));

    float rev0 = pos * invr0;
    float rev1 = pos * invr1;
    float f0 = rev0 - floorf(rev0);             // folds to v_fract_f32
    float f1 = rev1 - floorf(rev1);
    float sin0 = __builtin_amdgcn_sinf(f0);
    float cos0 = __builtin_amdgcn_cosf(f0);
    float sin1 = __builtin_amdgcn_sinf(f1);
    float cos1 = __builtin_amdgcn_cosf(f1);

    uint32_t b0 = threefry_bits_xor(n + 0u);
    uint32_t b1 = threefry_bits_xor(n + 1u);
    uint32_t b2 = threefry_bits_xor(n + 2u);
    uint32_t b3 = threefry_bits_xor(n + 3u);

    vf4 r;
    r.x = (e.x + sin0) * (b0 < KEEP_THRESH ? KEEP_SCALE : 0.0f);
    r.y = (e.y + cos0) * (b1 < KEEP_THRESH ? KEEP_SCALE : 0.0f);
    r.z = (e.z + sin1) * (b2 < KEEP_THRESH ? KEEP_SCALE : 0.0f);
    r.w = (e.w + cos1) * (b3 < KEEP_THRESH ? KEEP_SCALE : 0.0f);

    // Nontemporal: out is write-once, keep emb lines resident in L2/L3.
    __builtin_nontemporal_store(r, reinterpret_cast<vf4*>(out + n));
}

extern "C" void kernel_launch(void* const* d_in, const int* in_sizes, int n_in,
                              void* d_out, int out_size, void* d_ws, size_t ws_size,
                              hipStream_t stream) {
    const int* idx = (const int*)d_in[0];        // int32 token ids, 8*2048
    const float* emb = (const float*)d_in[1];    // fp32, 50257*1024
    float* out = (float*)d_out;                  // fp32, 2^24

    const uint32_t threads = 256;
    const uint32_t blocks = TOTAL / 1024u;       // 16384 rows, 1 row per block
    emb_pe_drop_kernel<<<dim3(blocks), dim3(threads), 0, stream>>>(idx, emb, out);
}